// Round 12
// baseline (90.912 us; speedup 1.0000x reference)
//
#include <hip/hip_runtime.h>
#include <math.h>

// Problem constants: gts/preds [4, 8192, 3] fp32; out [4] fp32.
#define BB 4
#define NPTS 8192
#define THREADS 256
#define NQ_TOTAL (2 * BB * NPTS)       // 65536 (dir,b,q) query slots
#define SLICES 8                       // ref-dim split; 16 KB LDS per block
#define RPS (NPTS / SLICES)            // 1024 refs per slice
#define QPW 32                         // queries per wave (ONE A fragment)
#define QPB_MIN (4 * QPW)              // 128 queries per block (4 waves)
#define QGROUPS (NPTS / QPB_MIN)       // 64 query groups per (dir,b)
#define NBLK_MIN (SLICES * 2 * BB * QGROUPS)   // 4096 blocks

typedef __attribute__((ext_vector_type(8)))  short bf16x8;   // MFMA A/B frag
typedef __attribute__((ext_vector_type(16))) float f32x16;   // MFMA C/D frag

// ws layout:
//   refpack: NQ_TOTAL uint4  bf16 [x,y,z,rr_hi,rr_lo,1,1,0]       1 MiB
//   qpack:   NQ_TOTAL uint4  bf16 [-2x,-2y,-2z,1,1,qq_hi,qq_lo,0] 1 MiB
//   minpart: SLICES * NQ_TOTAL float                              2 MiB
// MFMA dot(A_row,B_col) = -2 q.r + rr + qq = |q-r|^2 on bf16-rounded points.

__device__ __forceinline__ unsigned short f2bf(float f) {   // RNE f32->bf16
    unsigned u = __float_as_uint(f);
    u += 0x7FFF + ((u >> 16) & 1);
    return (unsigned short)(u >> 16);
}
__device__ __forceinline__ float bf2f(unsigned short h) {
    return __uint_as_float(((unsigned)h) << 16);
}

// ---------------------------------------------------------------------------
// Kernel 1: round coords to bf16, build A- and B-side fragments; zero out[].
// rr/qq computed in fp32 FROM THE ROUNDED coords and fed as 2-term bf16
// splits, so d^2 = |q~-r~|^2 up to ~2^-17 relative error.
// ---------------------------------------------------------------------------
__global__ __launch_bounds__(THREADS) void pack_kernel(
    const float* __restrict__ gts, const float* __restrict__ preds,
    uint4* __restrict__ refpack, uint4* __restrict__ qpack,
    float* __restrict__ out) {
    int idx = blockIdx.x * THREADS + threadIdx.x;
    if (idx < BB) out[idx] = 0.0f;
    if (idx >= NQ_TOTAL) return;
    int set  = idx / (BB * NPTS);          // 0 = gts, 1 = preds
    int pidx = idx - set * (BB * NPTS);
    const float* src = set ? preds : gts;
    unsigned short hx = f2bf(src[pidx * 3 + 0]);
    unsigned short hy = f2bf(src[pidx * 3 + 1]);
    unsigned short hz = f2bf(src[pidx * 3 + 2]);
    float fx = bf2f(hx), fy = bf2f(hy), fz = bf2f(hz);
    float rr = fmaf(fx, fx, fmaf(fy, fy, fz * fz));
    unsigned short hrr = f2bf(rr);
    unsigned short hlo = f2bf(rr - bf2f(hrr));
    const unsigned short ONE = 0x3F80;      // 1.0 bf16

    uint4 rv;                               // B slots: [x,y,z,rrhi,rrlo,1,1,0]
    rv.x = (unsigned)hx  | ((unsigned)hy  << 16);
    rv.y = (unsigned)hz  | ((unsigned)hrr << 16);
    rv.z = (unsigned)hlo | ((unsigned)ONE << 16);
    rv.w = (unsigned)ONE;
    refpack[idx] = rv;

    unsigned short nx = f2bf(-2.0f * fx);   // exact (coords already bf16)
    unsigned short ny = f2bf(-2.0f * fy);
    unsigned short nz = f2bf(-2.0f * fz);
    uint4 qv;                               // A slots: [-2x,-2y,-2z,1,1,qqhi,qqlo,0]
    qv.x = (unsigned)nx  | ((unsigned)ny  << 16);
    qv.y = (unsigned)nz  | ((unsigned)ONE << 16);
    qv.z = (unsigned)ONE | ((unsigned)hrr << 16);
    qv.w = (unsigned)hlo;
    qpack[idx] = qv;
}

// ---------------------------------------------------------------------------
// Kernel 2: MFMA min kernel, LOW-VGPR variant. One A fragment per wave
// (32 queries) -> only 2 live f32x16 MFMA results + 1 macc[16]; target ~84
// VGPRs so accumulators stay VGPR-resident (no AGPR round-trip) and 4
// waves/SIMD fit. Refs LDS-staged (16 KB/block); per iter: 2 ds_read_b128,
// 2 MFMA, 16 v_min3 (0.5 VALU op/pair). A's K slots 8-15 zero -> B lanes
// 32-63 don't-care -> unconditional full-wave reads.
// D layout (m74/m101): col = lane&31, row = (r&3)+8*(r>>2)+4*(lane>>5).
// ---------------------------------------------------------------------------
__global__ __launch_bounds__(THREADS) void min_kernel(
    const uint4* __restrict__ refpack, const uint4* __restrict__ qpack,
    float* __restrict__ minpart) {
    __shared__ uint4 sref[RPS];            // 16 KB

    int tid   = threadIdx.x;
    int blk   = blockIdx.x;
    int slice = blk >> 9;                  // / (2*BB*QGROUPS) = /512
    int rem   = blk & 511;
    int dir   = rem >> 8;
    int b     = (rem >> 6) & 3;
    int qg    = rem & 63;                  // query group of 128
    int qset  = dir ^ 1;                   // dir0: queries=preds(set1), refs=gts
    int rset  = dir;

    // Stage the ref slice: 1024 uint4, 4 coalesced rounds of 256 lanes.
    const uint4* rgl = refpack + (size_t)(rset * BB + b) * NPTS
                     + (size_t)slice * RPS;
    #pragma unroll
    for (int i = 0; i < RPS / THREADS; ++i)
        sref[i * THREADS + tid] = rgl[i * THREADS + tid];
    __syncthreads();

    int wid  = tid >> 6;
    int lane = tid & 63;
    int l31  = lane & 31;
    int half = lane >> 5;

    // One persistent A fragment (32 queries per wave).
    size_t qoff = (size_t)(qset * BB + b) * NPTS + (size_t)qg * QPB_MIN
                + (size_t)wid * QPW;
    bf16x8 a = {0, 0, 0, 0, 0, 0, 0, 0};
    if (lane < 32) a = ((const bf16x8*)qpack)[qoff + l31];

    f32x16 zeroc;
    #pragma unroll
    for (int r = 0; r < 16; ++r) zeroc[r] = 0.0f;

    float macc[16];
    #pragma unroll
    for (int r = 0; r < 16; ++r) macc[r] = 3.0e38f;

    const bf16x8* sp = (const bf16x8*)sref;
    #pragma unroll 4
    for (int t = 0; t < RPS / 64; ++t) {   // 16 iters, 64 refs x 32 queries
        bf16x8 b0 = sp[t * 64 + l31];
        bf16x8 b1 = sp[t * 64 + l31 + 32];
        f32x16 d0 = __builtin_amdgcn_mfma_f32_32x32x16_bf16(a, b0, zeroc, 0, 0, 0);
        f32x16 d1 = __builtin_amdgcn_mfma_f32_32x32x16_bf16(a, b1, zeroc, 0, 0, 0);
        #pragma unroll
        for (int r = 0; r < 16; ++r)
            macc[r] = fminf(fminf(d0[r], d1[r]), macc[r]);   // v_min3_f32
    }

    // Min across the 32 cols (lanes within each half), per row register.
    #pragma unroll
    for (int s = 1; s <= 16; s <<= 1) {
        #pragma unroll
        for (int r = 0; r < 16; ++r)
            macc[r] = fminf(macc[r], __shfl_xor(macc[r], s, 64));
    }

    // Lane r of each half writes row(r, half).
    float* mp = minpart + (size_t)slice * NQ_TOTAL
              + (size_t)(dir * BB + b) * NPTS + (size_t)qg * QPB_MIN
              + (size_t)wid * QPW;
    #pragma unroll
    for (int r = 0; r < 16; ++r) {
        int row = (r & 3) + 8 * (r >> 2) + 4 * half;
        if (l31 == r) mp[row] = macc[r];
    }
}

// ---------------------------------------------------------------------------
// Kernel 3: merge slices, sqrt, block-reduce, atomicAdd into out[b].
// ---------------------------------------------------------------------------
__global__ __launch_bounds__(THREADS) void merge_kernel(
    const float* __restrict__ minpart, float* __restrict__ out) {
    int q = blockIdx.x * THREADS + threadIdx.x;    // 0 .. NQ_TOTAL-1
    float m = minpart[q];
    #pragma unroll
    for (int s = 1; s < SLICES; ++s)
        m = fminf(m, minpart[(size_t)s * NQ_TOTAL + q]);
    float d = sqrtf(fmaxf(m, 0.0f));
    int b = (q >> 13) & 3;                         // uniform within a block

    float sum = d;
    #pragma unroll
    for (int off = 32; off > 0; off >>= 1)
        sum += __shfl_down(sum, off, 64);

    __shared__ float wsum[THREADS / 64];
    int lane = threadIdx.x & 63;
    int wid  = threadIdx.x >> 6;
    if (lane == 0) wsum[wid] = sum;
    __syncthreads();
    if (threadIdx.x == 0)
        atomicAdd(out + b, wsum[0] + wsum[1] + wsum[2] + wsum[3]);
}

extern "C" void kernel_launch(void* const* d_in, const int* in_sizes, int n_in,
                              void* d_out, int out_size, void* d_ws, size_t ws_size,
                              hipStream_t stream) {
    const float* gts   = (const float*)d_in[0];
    const float* preds = (const float*)d_in[1];
    float* out = (float*)d_out;

    char* ws = (char*)d_ws;
    uint4* refpack = (uint4*)ws;                                   // 1 MiB
    uint4* qpack   = (uint4*)(ws + (size_t)NQ_TOTAL * 16);         // 1 MiB
    float* minpart = (float*)(ws + (size_t)NQ_TOTAL * 32);         // 2 MiB

    pack_kernel<<<NQ_TOTAL / THREADS, THREADS, 0, stream>>>(
        gts, preds, refpack, qpack, out);

    min_kernel<<<NBLK_MIN, THREADS, 0, stream>>>(refpack, qpack, minpart);

    merge_kernel<<<NQ_TOTAL / THREADS, THREADS, 0, stream>>>(minpart, out);
}

// Round 13
// 83.477 us; speedup vs baseline: 1.0891x; 1.0891x over previous
//
#include <hip/hip_runtime.h>
#include <math.h>

// Problem constants: gts/preds [4, 8192, 3] fp32; out [4] fp32.
#define BB 4
#define NPTS 8192
#define THREADS 256
#define NQ_TOTAL (2 * BB * NPTS)       // 65536 (dir,b,q) query slots
#define SLICES 4                       // ref-dim split; 32 KB LDS per block
#define RPS (NPTS / SLICES)            // 2048 refs per slice
#define QPW 32                         // queries per wave (one B fragment)
#define QPB_MIN (4 * QPW)              // 128 queries per block (4 waves)
#define QGROUPS (NPTS / QPB_MIN)       // 64 query groups per (dir,b)
#define NBLK_MIN (SLICES * 2 * BB * QGROUPS)   // 2048 blocks

typedef __attribute__((ext_vector_type(8)))  short bf16x8;   // MFMA A/B frag
typedef __attribute__((ext_vector_type(16))) float f32x16;   // MFMA C/D frag

// ws layout:
//   refpack: NQ_TOTAL uint4  bf16 [x,y,z,rr_hi,rr_lo,1,1,0]       1 MiB
//   qpack:   NQ_TOTAL uint4  bf16 [-2x,-2y,-2z,1,1,qq_hi,qq_lo,0] 1 MiB
//   minpart: SLICES * NQ_TOTAL float                              1 MiB
// MFMA dot = -2 q.r + rr + qq = |q-r|^2 on bf16-rounded points.
// ROLE SWAP vs R10: A = refs (rows), B = queries (cols). B's K slots 8-15
// are zero (query frags end in 0, upper lanes zeroed) -> A's lanes 32-63
// are don't-care -> unconditional full-wave LDS reads for refs. Each lane's
// D regs hold 16 ref-rows for ITS query col -> min is register-local.

__device__ __forceinline__ unsigned short f2bf(float f) {   // RNE f32->bf16
    unsigned u = __float_as_uint(f);
    u += 0x7FFF + ((u >> 16) & 1);
    return (unsigned short)(u >> 16);
}
__device__ __forceinline__ float bf2f(unsigned short h) {
    return __uint_as_float(((unsigned)h) << 16);
}

// ---------------------------------------------------------------------------
// Kernel 1: round coords to bf16, build ref- and query-side fragments.
// rr/qq computed in fp32 FROM THE ROUNDED coords, fed as 2-term bf16 splits.
// ---------------------------------------------------------------------------
__global__ __launch_bounds__(THREADS) void pack_kernel(
    const float* __restrict__ gts, const float* __restrict__ preds,
    uint4* __restrict__ refpack, uint4* __restrict__ qpack,
    float* __restrict__ out) {
    int idx = blockIdx.x * THREADS + threadIdx.x;
    if (idx < BB) out[idx] = 0.0f;
    if (idx >= NQ_TOTAL) return;
    int set  = idx / (BB * NPTS);          // 0 = gts, 1 = preds
    int pidx = idx - set * (BB * NPTS);
    const float* src = set ? preds : gts;
    unsigned short hx = f2bf(src[pidx * 3 + 0]);
    unsigned short hy = f2bf(src[pidx * 3 + 1]);
    unsigned short hz = f2bf(src[pidx * 3 + 2]);
    float fx = bf2f(hx), fy = bf2f(hy), fz = bf2f(hz);
    float rr = fmaf(fx, fx, fmaf(fy, fy, fz * fz));
    unsigned short hrr = f2bf(rr);
    unsigned short hlo = f2bf(rr - bf2f(hrr));
    const unsigned short ONE = 0x3F80;      // 1.0 bf16

    uint4 rv;                               // ref slots: [x,y,z,rrhi,rrlo,1,1,0]
    rv.x = (unsigned)hx  | ((unsigned)hy  << 16);
    rv.y = (unsigned)hz  | ((unsigned)hrr << 16);
    rv.z = (unsigned)hlo | ((unsigned)ONE << 16);
    rv.w = (unsigned)ONE;
    refpack[idx] = rv;

    unsigned short nx = f2bf(-2.0f * fx);   // exact (coords already bf16)
    unsigned short ny = f2bf(-2.0f * fy);
    unsigned short nz = f2bf(-2.0f * fz);
    uint4 qv;                               // query slots: [-2x,-2y,-2z,1,1,qqhi,qqlo,0]
    qv.x = (unsigned)nx  | ((unsigned)ny  << 16);
    qv.y = (unsigned)nz  | ((unsigned)ONE << 16);
    qv.z = (unsigned)ONE | ((unsigned)hrr << 16);
    qv.w = (unsigned)hlo;
    qpack[idx] = qv;
}

// ---------------------------------------------------------------------------
// Kernel 2: MFMA min kernel, ROLE-SWAPPED. B = this lane's query (persistent,
// lanes 32-63 zero). A = 32 refs/tile from LDS, full-wave unconditional
// reads (2 lanes per address = free broadcast). D[row=ref][col=query=l31]:
// lane-local min into 2 scalar accumulators (16 v_min3/iter, same op count
// as R10) — the 160-shfl butterfly tail becomes ONE shfl_xor + 1 min, and
// the store is a single coalesced 32-lane write.
// D layout (m74/m101): col = lane&31, row = (r&3)+8*(r>>2)+4*(lane>>5).
// ---------------------------------------------------------------------------
__global__ __launch_bounds__(THREADS) void min_kernel(
    const uint4* __restrict__ refpack, const uint4* __restrict__ qpack,
    float* __restrict__ minpart) {
    __shared__ uint4 sref[RPS];            // 32 KB

    int tid   = threadIdx.x;
    int blk   = blockIdx.x;
    int slice = blk >> 9;                  // / (2*BB*QGROUPS) = /512
    int rem   = blk & 511;
    int dir   = rem >> 8;
    int b     = (rem >> 6) & 3;
    int qg    = rem & 63;                  // query group of 128
    int qset  = dir ^ 1;                   // dir0: queries=preds(set1), refs=gts
    int rset  = dir;

    // Stage the ref slice: 2048 uint4, 8 coalesced rounds of 256 lanes.
    const uint4* rgl = refpack + (size_t)(rset * BB + b) * NPTS
                     + (size_t)slice * RPS;
    #pragma unroll
    for (int i = 0; i < RPS / THREADS; ++i)
        sref[i * THREADS + tid] = rgl[i * THREADS + tid];
    __syncthreads();

    int wid  = tid >> 6;
    int lane = tid & 63;
    int l31  = lane & 31;
    int half = lane >> 5;

    // B fragment: lane l31 = query col l31 (K slots 0-7); lanes 32-63 zero.
    size_t qoff = (size_t)(qset * BB + b) * NPTS + (size_t)qg * QPB_MIN
                + (size_t)wid * QPW;
    bf16x8 bq = {0, 0, 0, 0, 0, 0, 0, 0};
    if (lane < 32) bq = ((const bf16x8*)qpack)[qoff + l31];

    f32x16 zeroc;
    #pragma unroll
    for (int r = 0; r < 16; ++r) zeroc[r] = 0.0f;

    float macc0 = 3.0e38f, macc1 = 3.0e38f;   // two chains for ILP

    const bf16x8* sp = (const bf16x8*)sref;
    #pragma unroll 4
    for (int t = 0; t < RPS / 64; ++t) {   // 32 iters, 64 refs x 32 queries
        bf16x8 a0 = sp[t * 64 + l31];
        bf16x8 a1 = sp[t * 64 + 32 + l31];
        f32x16 d0 = __builtin_amdgcn_mfma_f32_32x32x16_bf16(a0, bq, zeroc, 0, 0, 0);
        f32x16 d1 = __builtin_amdgcn_mfma_f32_32x32x16_bf16(a1, bq, zeroc, 0, 0, 0);
        #pragma unroll
        for (int r = 0; r < 16; r += 2) {
            macc0 = fminf(fminf(d0[r], d0[r + 1]), macc0);   // v_min3_f32
            macc1 = fminf(fminf(d1[r], d1[r + 1]), macc1);
        }
    }

    // Each half covered a disjoint set of 16 ref-rows per MFMA; combine the
    // two chains, then the two halves (lane^32 holds the other row set).
    float macc = fminf(macc0, macc1);
    macc = fminf(macc, __shfl_xor(macc, 32, 64));

    // Coalesced store: lanes 0-31 write this wave's 32 query mins.
    float* mp = minpart + (size_t)slice * NQ_TOTAL
              + (size_t)(dir * BB + b) * NPTS + (size_t)qg * QPB_MIN
              + (size_t)wid * QPW;
    if (lane < 32) mp[l31] = macc;
}

// ---------------------------------------------------------------------------
// Kernel 3: merge slices, sqrt, block-reduce, atomicAdd into out[b].
// ---------------------------------------------------------------------------
__global__ __launch_bounds__(THREADS) void merge_kernel(
    const float* __restrict__ minpart, float* __restrict__ out) {
    int q = blockIdx.x * THREADS + threadIdx.x;    // 0 .. NQ_TOTAL-1
    float m = minpart[q];
    #pragma unroll
    for (int s = 1; s < SLICES; ++s)
        m = fminf(m, minpart[(size_t)s * NQ_TOTAL + q]);
    float d = sqrtf(fmaxf(m, 0.0f));
    int b = (q >> 13) & 3;                         // uniform within a block

    float sum = d;
    #pragma unroll
    for (int off = 32; off > 0; off >>= 1)
        sum += __shfl_down(sum, off, 64);

    __shared__ float wsum[THREADS / 64];
    int lane = threadIdx.x & 63;
    int wid  = threadIdx.x >> 6;
    if (lane == 0) wsum[wid] = sum;
    __syncthreads();
    if (threadIdx.x == 0)
        atomicAdd(out + b, wsum[0] + wsum[1] + wsum[2] + wsum[3]);
}

extern "C" void kernel_launch(void* const* d_in, const int* in_sizes, int n_in,
                              void* d_out, int out_size, void* d_ws, size_t ws_size,
                              hipStream_t stream) {
    const float* gts   = (const float*)d_in[0];
    const float* preds = (const float*)d_in[1];
    float* out = (float*)d_out;

    char* ws = (char*)d_ws;
    uint4* refpack = (uint4*)ws;                                   // 1 MiB
    uint4* qpack   = (uint4*)(ws + (size_t)NQ_TOTAL * 16);         // 1 MiB
    float* minpart = (float*)(ws + (size_t)NQ_TOTAL * 32);         // 1 MiB

    pack_kernel<<<NQ_TOTAL / THREADS, THREADS, 0, stream>>>(
        gts, preds, refpack, qpack, out);

    min_kernel<<<NBLK_MIN, THREADS, 0, stream>>>(refpack, qpack, minpart);

    merge_kernel<<<NQ_TOTAL / THREADS, THREADS, 0, stream>>>(minpart, out);
}